// Round 16
// baseline (366.310 us; speedup 1.0000x reference)
//
#include <hip/hip_runtime.h>
#include <hip/hip_bf16.h>
#include <math.h>

#define NEG_SLOPE 0.2f
#define GAT_EPS 1e-16f

__device__ __forceinline__ float lrelu(float v) {
    return v > 0.f ? v : NEG_SLOPE * v;
}

// ---------------------------------------------------------------------------
// Fused independent prep: blocks [0,eb) do edge-rank (atomic histogram of dst
// + per-edge slot index); blocks [eb, eb+nb4) do gemm1
// (h1 = x@W1 + attention dots). The two stages share no data.
// h1 is stored as bf16: it is a write-once/gather-many payload table, and
// halving its row size halves agg1's dominant L2/HBM traffic (round-10
// counters: FETCH = 8 x |h1| from per-XCD L2 duplication).
// ---------------------------------------------------------------------------
__global__ __launch_bounds__(256) void prep_kernel(
    const int* __restrict__ ei, int E,
    int* __restrict__ count, int* __restrict__ rank,
    const float* __restrict__ x, const float* __restrict__ W1,
    const float* __restrict__ a_src1, const float* __restrict__ a_dst1,
    __hip_bfloat16* __restrict__ h1, float* __restrict__ es1,
    float* __restrict__ ed1, int N, int eb)
{
    if ((int)blockIdx.x < eb) {
        int e = blockIdx.x * 256 + threadIdx.x;
        if (e < E) rank[e] = atomicAdd(&count[ei[E + e]], 1);
        return;
    }

    __shared__ float Ws[128 * 64];     // 32 KB
    __shared__ float xs[4][128];       // 2 KB

    int b = blockIdx.x - eb;
    int t = threadIdx.x;
    for (int i = t; i < 128 * 64; i += 256) Ws[i] = W1[i];

    int w    = t >> 6;
    int lane = t & 63;
    int n    = b * 4 + w;

    if (n < N) {
        xs[w][lane]      = x[(size_t)n * 128 + lane];
        xs[w][lane + 64] = x[(size_t)n * 128 + lane + 64];
    }
    __syncthreads();

    if (n < N) {
        float acc = 0.f;
        #pragma unroll
        for (int k = 0; k < 128; ++k)
            acc = fmaf(xs[w][k], Ws[k * 64 + lane], acc);
        h1[(size_t)n * 64 + lane] = __float2bfloat16(acc);

        float ps = acc * a_src1[lane];
        float pd = acc * a_dst1[lane];
        #pragma unroll
        for (int m = 1; m < 8; m <<= 1) {
            ps += __shfl_xor(ps, m, 64);
            pd += __shfl_xor(pd, m, 64);
        }
        if ((lane & 7) == 0) {
            es1[(size_t)n * 8 + (lane >> 3)] = ps;
            ed1[(size_t)n * 8 + (lane >> 3)] = pd;
        }
    }
}

// ---------------------------------------------------------------------------
// Single-kernel exclusive scan of count[0..N) -> row_start[0..N].
// One block of 1024 threads; serial chunk sum -> Hillis-Steele -> chunk walk.
// ---------------------------------------------------------------------------
__global__ __launch_bounds__(1024) void scanall_kernel(
    const int* __restrict__ count, int* __restrict__ row_start, int N, int E)
{
    __shared__ int part[1024];
    int t = threadIdx.x;
    int chunk = (N + 1023) / 1024;
    int lo = t * chunk; if (lo > N) lo = N;
    int hi = lo + chunk; if (hi > N) hi = N;

    int sum = 0;
    for (int i = lo; i < hi; ++i) sum += count[i];
    part[t] = sum;
    __syncthreads();
    #pragma unroll
    for (int off = 1; off < 1024; off <<= 1) {
        int add = (t >= off) ? part[t - off] : 0;
        __syncthreads();
        part[t] += add;
        __syncthreads();
    }
    int run = part[t] - sum;   // exclusive prefix of this chunk
    for (int i = lo; i < hi; ++i) {
        row_start[i] = run;
        run += count[i];
    }
    if (t == 0) row_start[N] = E;
}

// ---------------------------------------------------------------------------
// Scatter src ids into dst-sorted order (no atomics).
// ---------------------------------------------------------------------------
__global__ __launch_bounds__(256) void scatter_kernel(
    const int* __restrict__ ei, int E, const int* __restrict__ row_start,
    const int* __restrict__ rank, int* __restrict__ sorted_src)
{
    int e = blockIdx.x * 256 + threadIdx.x;
    if (e >= E) return;
    int d = ei[E + e];
    sorted_src[row_start[d] + rank[e]] = ei[e];
}

// ---------------------------------------------------------------------------
// Layer-1 aggregation + epilogue + GEMM2 + layer-2 dots, fused.
// One wave per node; lane owns output channel (h = lane>>3).
// h1 gathered as bf16 (halved row traffic); accumulation in f32.
// g written as bf16 for agg2's gather.
// ---------------------------------------------------------------------------
__global__ __launch_bounds__(256) void agg1_kernel(
    const int* __restrict__ row_start, const int* __restrict__ sorted_src,
    const __hip_bfloat16* __restrict__ h1, const float* __restrict__ es1,
    const float* __restrict__ ed1, const float* __restrict__ b1,
    const float* __restrict__ W2, const float* __restrict__ a_src2,
    const float* __restrict__ a_dst2,
    __hip_bfloat16* __restrict__ g, float* __restrict__ es2,
    float* __restrict__ ed2, int N)
{
    __shared__ float W2s[64 * 40];   // 10 KB
    __shared__ float h2s[4][64];

    int t = threadIdx.x;
    for (int i = t; i < 64 * 40; i += 256) W2s[i] = W2[i];

    int w    = t >> 6;
    int lane = t & 63;
    int n    = blockIdx.x * 4 + w;
    int h    = lane >> 3;

    if (n < N) {
        int lo = row_start[n], hi = row_start[n + 1];
        float edh = ed1[(size_t)n * 8 + h];
        float acc = 0.f, den = 0.f;
        int e = lo;
        for (; e + 4 <= hi; e += 4) {
            int s0 = sorted_src[e],     s1 = sorted_src[e + 1];
            int s2 = sorted_src[e + 2], s3 = sorted_src[e + 3];
            float q0 = es1[(size_t)s0 * 8 + h], q1 = es1[(size_t)s1 * 8 + h];
            float q2 = es1[(size_t)s2 * 8 + h], q3 = es1[(size_t)s3 * 8 + h];
            float v0 = __bfloat162float(h1[(size_t)s0 * 64 + lane]);
            float v1 = __bfloat162float(h1[(size_t)s1 * 64 + lane]);
            float v2 = __bfloat162float(h1[(size_t)s2 * 64 + lane]);
            float v3 = __bfloat162float(h1[(size_t)s3 * 64 + lane]);
            float p0 = __expf(lrelu(q0 + edh)), p1 = __expf(lrelu(q1 + edh));
            float p2 = __expf(lrelu(q2 + edh)), p3 = __expf(lrelu(q3 + edh));
            acc = fmaf(v0, p0, acc); den += p0;
            acc = fmaf(v1, p1, acc); den += p1;
            acc = fmaf(v2, p2, acc); den += p2;
            acc = fmaf(v3, p3, acc); den += p3;
        }
        for (; e < hi; ++e) {
            int s = sorted_src[e];
            float p = __expf(lrelu(es1[(size_t)s * 8 + h] + edh));
            acc = fmaf(__bfloat162float(h1[(size_t)s * 64 + lane]), p, acc);
            den += p;
        }
        float v = acc / (den + GAT_EPS) + b1[lane];
        h2s[w][lane] = v > 0.f ? v : 0.f;
    }
    __syncthreads();

    if (n < N) {
        float gv = 0.f;
        if (lane < 40) {
            #pragma unroll
            for (int k = 0; k < 64; ++k)
                gv = fmaf(h2s[w][k], W2s[k * 40 + lane], gv);
            g[(size_t)n * 40 + lane] = __float2bfloat16(gv);
        }
        float ps = (lane < 40) ? gv * a_src2[lane] : 0.f;
        float pd = (lane < 40) ? gv * a_dst2[lane] : 0.f;
        #pragma unroll
        for (int m = 1; m < 64; m <<= 1) {
            ps += __shfl_xor(ps, m, 64);
            pd += __shfl_xor(pd, m, 64);
        }
        if (lane == 0) { es2[n] = ps; ed2[n] = pd; }
    }
}

// ---------------------------------------------------------------------------
// Layer-2 aggregation + final log_softmax, fused. One wave per node.
// g gathered as bf16; accumulation and log_softmax in f32.
// ---------------------------------------------------------------------------
__global__ __launch_bounds__(256) void agg2_kernel(
    const int* __restrict__ row_start, const int* __restrict__ sorted_src,
    const __hip_bfloat16* __restrict__ g, const float* __restrict__ es2,
    const float* __restrict__ ed2, const float* __restrict__ b2,
    float* __restrict__ out, int N)
{
    int t = threadIdx.x;
    int w = t >> 6, lane = t & 63;
    int n = blockIdx.x * 4 + w;
    if (n >= N) return;

    int lo = row_start[n], hi = row_start[n + 1];
    float dn = ed2[n];
    float acc = 0.f, den = 0.f;
    int e = lo;
    for (; e + 4 <= hi; e += 4) {
        int s0 = sorted_src[e],     s1 = sorted_src[e + 1];
        int s2 = sorted_src[e + 2], s3 = sorted_src[e + 3];
        float q0 = es2[s0], q1 = es2[s1], q2 = es2[s2], q3 = es2[s3];
        float v0 = 0.f, v1 = 0.f, v2 = 0.f, v3 = 0.f;
        if (lane < 40) {
            v0 = __bfloat162float(g[(size_t)s0 * 40 + lane]);
            v1 = __bfloat162float(g[(size_t)s1 * 40 + lane]);
            v2 = __bfloat162float(g[(size_t)s2 * 40 + lane]);
            v3 = __bfloat162float(g[(size_t)s3 * 40 + lane]);
        }
        float p0 = __expf(lrelu(q0 + dn)), p1 = __expf(lrelu(q1 + dn));
        float p2 = __expf(lrelu(q2 + dn)), p3 = __expf(lrelu(q3 + dn));
        acc = fmaf(v0, p0, acc); den += p0;
        acc = fmaf(v1, p1, acc); den += p1;
        acc = fmaf(v2, p2, acc); den += p2;
        acc = fmaf(v3, p3, acc); den += p3;
    }
    for (; e < hi; ++e) {
        int s = sorted_src[e];
        float p = __expf(lrelu(es2[s] + dn));
        den += p;
        if (lane < 40)
            acc = fmaf(__bfloat162float(g[(size_t)s * 40 + lane]), p, acc);
    }

    float val = 0.f, v = -INFINITY;
    if (lane < 40) {
        val = acc / (den + GAT_EPS) + b2[lane];
        v = val;
    }
    float mx = v;
    #pragma unroll
    for (int m = 1; m < 64; m <<= 1)
        mx = fmaxf(mx, __shfl_xor(mx, m, 64));
    float ex = (lane < 40) ? __expf(val - mx) : 0.f;
    #pragma unroll
    for (int m = 1; m < 64; m <<= 1)
        ex += __shfl_xor(ex, m, 64);
    if (lane < 40)
        out[(size_t)n * 40 + lane] = val - mx - logf(ex);
}

// ---------------------------------------------------------------------------
extern "C" void kernel_launch(void* const* d_in, const int* in_sizes, int n_in,
                              void* d_out, int out_size, void* d_ws, size_t ws_size,
                              hipStream_t stream)
{
    const float* x      = (const float*)d_in[0];
    const int*   ei     = (const int*)d_in[1];
    const float* W1     = (const float*)d_in[2];
    const float* a_src1 = (const float*)d_in[3];
    const float* a_dst1 = (const float*)d_in[4];
    const float* b1     = (const float*)d_in[5];
    const float* W2     = (const float*)d_in[6];
    const float* a_src2 = (const float*)d_in[7];
    const float* a_dst2 = (const float*)d_in[8];
    const float* b2     = (const float*)d_in[9];
    float* out = (float*)d_out;

    int N = in_sizes[0] / 128;
    int E = in_sizes[1] / 2;
    int nb4 = (N + 3) / 4;
    int eb  = (E + 255) / 256;

    float* ws = (float*)d_ws;
    size_t off = 0;
    __hip_bfloat16* h1 = (__hip_bfloat16*)(ws + off); off += (size_t)N * 32; // 64 bf16/node
    float* es1 = ws + off; off += (size_t)N * 8;
    float* ed1 = ws + off; off += (size_t)N * 8;
    __hip_bfloat16* g  = (__hip_bfloat16*)(ws + off); off += (size_t)N * 20; // 40 bf16/node
    float* es2 = ws + off; off += (size_t)N;
    float* ed2 = ws + off; off += (size_t)N;
    int* row_start  = (int*)(ws + off); off += (size_t)N + 1;
    int* sorted_src = (int*)(ws + off); off += (size_t)E;
    int* rank       = (int*)(ws + off); off += (size_t)E;
    int* count      = (int*)(ws + off); off += (size_t)N;   // must be zeroed

    hipMemsetAsync(count, 0, (size_t)N * sizeof(int), stream);

    prep_kernel<<<eb + nb4, 256, 0, stream>>>(ei, E, count, rank,
                                              x, W1, a_src1, a_dst1,
                                              h1, es1, ed1, N, eb);
    scanall_kernel<<<1, 1024, 0, stream>>>(count, row_start, N, E);
    scatter_kernel<<<eb, 256, 0, stream>>>(ei, E, row_start, rank, sorted_src);
    agg1_kernel<<<nb4, 256, 0, stream>>>(row_start, sorted_src, h1, es1, ed1,
                                         b1, W2, a_src2, a_dst2, g, es2, ed2, N);
    agg2_kernel<<<nb4, 256, 0, stream>>>(row_start, sorted_src, g, es2, ed2,
                                         b2, out, N);
}

// Round 18
// 300.054 us; speedup vs baseline: 1.2208x; 1.2208x over previous
//
#include <hip/hip_runtime.h>
#include <hip/hip_bf16.h>
#include <math.h>

#define NEG_SLOPE 0.2f
#define GAT_EPS 1e-16f

__device__ __forceinline__ float lrelu(float v) {
    return v > 0.f ? v : NEG_SLOPE * v;
}

// ---------------------------------------------------------------------------
// h1 = x @ W1 (bf16 payload table out) + per-node attention dots (f32).
// Block = 256 = 4 nodes x 64 lanes. W1 (32KB) in LDS.
// Kept SEPARATE from rank_kernel: fusing them (round 16) dropped the rank
// phase to 4 blocks/CU via this kernel's 34KB LDS -> 91us vs sum ~70us.
// ---------------------------------------------------------------------------
__global__ __launch_bounds__(256) void gemm1_kernel(
    const float* __restrict__ x, const float* __restrict__ W1,
    const float* __restrict__ a_src1, const float* __restrict__ a_dst1,
    __hip_bfloat16* __restrict__ h1, float* __restrict__ es1,
    float* __restrict__ ed1, int N)
{
    __shared__ float Ws[128 * 64];     // 32 KB
    __shared__ float xs[4][128];       // 2 KB

    int t = threadIdx.x;
    for (int i = t; i < 128 * 64; i += 256) Ws[i] = W1[i];

    int w    = t >> 6;
    int lane = t & 63;
    int n    = blockIdx.x * 4 + w;

    if (n < N) {
        xs[w][lane]      = x[(size_t)n * 128 + lane];
        xs[w][lane + 64] = x[(size_t)n * 128 + lane + 64];
    }
    __syncthreads();

    if (n < N) {
        float acc = 0.f;
        #pragma unroll
        for (int k = 0; k < 128; ++k)
            acc = fmaf(xs[w][k], Ws[k * 64 + lane], acc);
        h1[(size_t)n * 64 + lane] = __float2bfloat16(acc);

        float ps = acc * a_src1[lane];
        float pd = acc * a_dst1[lane];
        #pragma unroll
        for (int m = 1; m < 8; m <<= 1) {
            ps += __shfl_xor(ps, m, 64);
            pd += __shfl_xor(pd, m, 64);
        }
        if ((lane & 7) == 0) {
            es1[(size_t)n * 8 + (lane >> 3)] = ps;
            ed1[(size_t)n * 8 + (lane >> 3)] = pd;
        }
    }
}

// ---------------------------------------------------------------------------
// CSR build 1: per-edge rank within its dst segment + histogram.
// No LDS, 20 VGPR -> full occupancy for the latency-bound atomics.
// ---------------------------------------------------------------------------
__global__ __launch_bounds__(256) void rank_kernel(
    const int* __restrict__ ei, int E,
    int* __restrict__ count, int* __restrict__ rank)
{
    int e = blockIdx.x * 256 + threadIdx.x;
    if (e >= E) return;
    rank[e] = atomicAdd(&count[ei[E + e]], 1);
}

// ---------------------------------------------------------------------------
// CSR build 2a: per-block inclusive scan (Hillis-Steele in LDS).
// ---------------------------------------------------------------------------
__global__ __launch_bounds__(256) void scan1_kernel(
    const int* __restrict__ count, int* __restrict__ excl,
    int* __restrict__ btotal, int N)
{
    __shared__ int tmp[256];
    int t = threadIdx.x;
    int i = blockIdx.x * 256 + t;
    int v = (i < N) ? count[i] : 0;
    tmp[t] = v;
    __syncthreads();
    #pragma unroll
    for (int off = 1; off < 256; off <<= 1) {
        int add = (t >= off) ? tmp[t - off] : 0;
        __syncthreads();
        tmp[t] += add;
        __syncthreads();
    }
    if (i < N) excl[i] = tmp[t] - v;
    if (t == 255) btotal[blockIdx.x] = tmp[255];
}

// ---------------------------------------------------------------------------
// CSR build 2b: exclusive scan of block totals (nb <= 256, one block).
// ---------------------------------------------------------------------------
__global__ __launch_bounds__(256) void scan2_kernel(int* __restrict__ btotal, int nb)
{
    __shared__ int tmp[256];
    int t = threadIdx.x;
    int v = (t < nb) ? btotal[t] : 0;
    tmp[t] = v;
    __syncthreads();
    #pragma unroll
    for (int off = 1; off < 256; off <<= 1) {
        int add = (t >= off) ? tmp[t - off] : 0;
        __syncthreads();
        tmp[t] += add;
        __syncthreads();
    }
    if (t < nb) btotal[t] = tmp[t] - v;
}

// ---------------------------------------------------------------------------
// CSR build 2c: row_start[i] = excl[i] + btotal[block]; row_start[N] = E.
// ---------------------------------------------------------------------------
__global__ __launch_bounds__(256) void scan3_kernel(
    const int* __restrict__ excl, const int* __restrict__ btotal,
    int* __restrict__ row_start, int N, int E)
{
    int i = blockIdx.x * 256 + threadIdx.x;
    if (i < N) row_start[i] = excl[i] + btotal[blockIdx.x];
    if (i == 0) row_start[N] = E;
}

// ---------------------------------------------------------------------------
// CSR build 3: scatter src ids into dst-sorted order (no atomics).
// ---------------------------------------------------------------------------
__global__ __launch_bounds__(256) void scatter_kernel(
    const int* __restrict__ ei, int E, const int* __restrict__ row_start,
    const int* __restrict__ rank, int* __restrict__ sorted_src)
{
    int e = blockIdx.x * 256 + threadIdx.x;
    if (e >= E) return;
    int d = ei[E + e];
    sorted_src[row_start[d] + rank[e]] = ei[e];
}

// ---------------------------------------------------------------------------
// Layer-1 aggregation + epilogue + GEMM2 + layer-2 dots, fused.
// One wave per node; lane owns output channel (h = lane>>3).
// h1 gathered as bf16 (halved row traffic vs f32); accumulation f32.
// g written as bf16 for agg2's gather.
// ---------------------------------------------------------------------------
__global__ __launch_bounds__(256) void agg1_kernel(
    const int* __restrict__ row_start, const int* __restrict__ sorted_src,
    const __hip_bfloat16* __restrict__ h1, const float* __restrict__ es1,
    const float* __restrict__ ed1, const float* __restrict__ b1,
    const float* __restrict__ W2, const float* __restrict__ a_src2,
    const float* __restrict__ a_dst2,
    __hip_bfloat16* __restrict__ g, float* __restrict__ es2,
    float* __restrict__ ed2, int N)
{
    __shared__ float W2s[64 * 40];   // 10 KB
    __shared__ float h2s[4][64];

    int t = threadIdx.x;
    for (int i = t; i < 64 * 40; i += 256) W2s[i] = W2[i];

    int w    = t >> 6;
    int lane = t & 63;
    int n    = blockIdx.x * 4 + w;
    int h    = lane >> 3;

    if (n < N) {
        int lo = row_start[n], hi = row_start[n + 1];
        float edh = ed1[(size_t)n * 8 + h];
        float acc = 0.f, den = 0.f;
        int e = lo;
        for (; e + 4 <= hi; e += 4) {
            int s0 = sorted_src[e],     s1 = sorted_src[e + 1];
            int s2 = sorted_src[e + 2], s3 = sorted_src[e + 3];
            float q0 = es1[(size_t)s0 * 8 + h], q1 = es1[(size_t)s1 * 8 + h];
            float q2 = es1[(size_t)s2 * 8 + h], q3 = es1[(size_t)s3 * 8 + h];
            float v0 = __bfloat162float(h1[(size_t)s0 * 64 + lane]);
            float v1 = __bfloat162float(h1[(size_t)s1 * 64 + lane]);
            float v2 = __bfloat162float(h1[(size_t)s2 * 64 + lane]);
            float v3 = __bfloat162float(h1[(size_t)s3 * 64 + lane]);
            float p0 = __expf(lrelu(q0 + edh)), p1 = __expf(lrelu(q1 + edh));
            float p2 = __expf(lrelu(q2 + edh)), p3 = __expf(lrelu(q3 + edh));
            acc = fmaf(v0, p0, acc); den += p0;
            acc = fmaf(v1, p1, acc); den += p1;
            acc = fmaf(v2, p2, acc); den += p2;
            acc = fmaf(v3, p3, acc); den += p3;
        }
        for (; e < hi; ++e) {
            int s = sorted_src[e];
            float p = __expf(lrelu(es1[(size_t)s * 8 + h] + edh));
            acc = fmaf(__bfloat162float(h1[(size_t)s * 64 + lane]), p, acc);
            den += p;
        }
        float v = acc / (den + GAT_EPS) + b1[lane];
        h2s[w][lane] = v > 0.f ? v : 0.f;
    }
    __syncthreads();

    if (n < N) {
        float gv = 0.f;
        if (lane < 40) {
            #pragma unroll
            for (int k = 0; k < 64; ++k)
                gv = fmaf(h2s[w][k], W2s[k * 40 + lane], gv);
            g[(size_t)n * 40 + lane] = __float2bfloat16(gv);
        }
        float ps = (lane < 40) ? gv * a_src2[lane] : 0.f;
        float pd = (lane < 40) ? gv * a_dst2[lane] : 0.f;
        #pragma unroll
        for (int m = 1; m < 64; m <<= 1) {
            ps += __shfl_xor(ps, m, 64);
            pd += __shfl_xor(pd, m, 64);
        }
        if (lane == 0) { es2[n] = ps; ed2[n] = pd; }
    }
}

// ---------------------------------------------------------------------------
// Layer-2 aggregation + final log_softmax, fused. One wave per node.
// g gathered as bf16; accumulation and log_softmax in f32.
// ---------------------------------------------------------------------------
__global__ __launch_bounds__(256) void agg2_kernel(
    const int* __restrict__ row_start, const int* __restrict__ sorted_src,
    const __hip_bfloat16* __restrict__ g, const float* __restrict__ es2,
    const float* __restrict__ ed2, const float* __restrict__ b2,
    float* __restrict__ out, int N)
{
    int t = threadIdx.x;
    int w = t >> 6, lane = t & 63;
    int n = blockIdx.x * 4 + w;
    if (n >= N) return;

    int lo = row_start[n], hi = row_start[n + 1];
    float dn = ed2[n];
    float acc = 0.f, den = 0.f;
    int e = lo;
    for (; e + 4 <= hi; e += 4) {
        int s0 = sorted_src[e],     s1 = sorted_src[e + 1];
        int s2 = sorted_src[e + 2], s3 = sorted_src[e + 3];
        float q0 = es2[s0], q1 = es2[s1], q2 = es2[s2], q3 = es2[s3];
        float v0 = 0.f, v1 = 0.f, v2 = 0.f, v3 = 0.f;
        if (lane < 40) {
            v0 = __bfloat162float(g[(size_t)s0 * 40 + lane]);
            v1 = __bfloat162float(g[(size_t)s1 * 40 + lane]);
            v2 = __bfloat162float(g[(size_t)s2 * 40 + lane]);
            v3 = __bfloat162float(g[(size_t)s3 * 40 + lane]);
        }
        float p0 = __expf(lrelu(q0 + dn)), p1 = __expf(lrelu(q1 + dn));
        float p2 = __expf(lrelu(q2 + dn)), p3 = __expf(lrelu(q3 + dn));
        acc = fmaf(v0, p0, acc); den += p0;
        acc = fmaf(v1, p1, acc); den += p1;
        acc = fmaf(v2, p2, acc); den += p2;
        acc = fmaf(v3, p3, acc); den += p3;
    }
    for (; e < hi; ++e) {
        int s = sorted_src[e];
        float p = __expf(lrelu(es2[s] + dn));
        den += p;
        if (lane < 40)
            acc = fmaf(__bfloat162float(g[(size_t)s * 40 + lane]), p, acc);
    }

    float val = 0.f, v = -INFINITY;
    if (lane < 40) {
        val = acc / (den + GAT_EPS) + b2[lane];
        v = val;
    }
    float mx = v;
    #pragma unroll
    for (int m = 1; m < 64; m <<= 1)
        mx = fmaxf(mx, __shfl_xor(mx, m, 64));
    float ex = (lane < 40) ? __expf(val - mx) : 0.f;
    #pragma unroll
    for (int m = 1; m < 64; m <<= 1)
        ex += __shfl_xor(ex, m, 64);
    if (lane < 40)
        out[(size_t)n * 40 + lane] = val - mx - logf(ex);
}

// ---------------------------------------------------------------------------
extern "C" void kernel_launch(void* const* d_in, const int* in_sizes, int n_in,
                              void* d_out, int out_size, void* d_ws, size_t ws_size,
                              hipStream_t stream)
{
    const float* x      = (const float*)d_in[0];
    const int*   ei     = (const int*)d_in[1];
    const float* W1     = (const float*)d_in[2];
    const float* a_src1 = (const float*)d_in[3];
    const float* a_dst1 = (const float*)d_in[4];
    const float* b1     = (const float*)d_in[5];
    const float* W2     = (const float*)d_in[6];
    const float* a_src2 = (const float*)d_in[7];
    const float* a_dst2 = (const float*)d_in[8];
    const float* b2     = (const float*)d_in[9];
    float* out = (float*)d_out;

    int N = in_sizes[0] / 128;
    int E = in_sizes[1] / 2;
    int nb  = (N + 255) / 256;          // 196 blocks for N=50000 (<=256 req'd by scan2)
    int nb4 = (N + 3) / 4;
    int eb  = (E + 255) / 256;

    float* ws = (float*)d_ws;
    size_t off = 0;
    __hip_bfloat16* h1 = (__hip_bfloat16*)(ws + off); off += (size_t)N * 32; // 64 bf16/node
    float* es1 = ws + off; off += (size_t)N * 8;
    float* ed1 = ws + off; off += (size_t)N * 8;
    __hip_bfloat16* g  = (__hip_bfloat16*)(ws + off); off += (size_t)N * 20; // 40 bf16/node
    float* es2 = ws + off; off += (size_t)N;
    float* ed2 = ws + off; off += (size_t)N;
    int* row_start  = (int*)(ws + off); off += (size_t)N + 1;
    int* sorted_src = (int*)(ws + off); off += (size_t)E;
    int* rank       = (int*)(ws + off); off += (size_t)E;
    int* excl       = (int*)(ws + off); off += (size_t)N;
    int* btotal     = (int*)(ws + off); off += 256;
    int* count      = (int*)(ws + off); off += (size_t)N;   // must be zeroed

    hipMemsetAsync(count, 0, (size_t)N * sizeof(int), stream);

    rank_kernel<<<eb, 256, 0, stream>>>(ei, E, count, rank);
    scan1_kernel<<<nb, 256, 0, stream>>>(count, excl, btotal, N);
    scan2_kernel<<<1, 256, 0, stream>>>(btotal, nb);
    scan3_kernel<<<nb, 256, 0, stream>>>(excl, btotal, row_start, N, E);
    scatter_kernel<<<eb, 256, 0, stream>>>(ei, E, row_start, rank, sorted_src);
    gemm1_kernel<<<nb4, 256, 0, stream>>>(x, W1, a_src1, a_dst1, h1, es1, ed1, N);
    agg1_kernel<<<nb4, 256, 0, stream>>>(row_start, sorted_src, h1, es1, ed1,
                                         b1, W2, a_src2, a_dst2, g, es2, ed2, N);
    agg2_kernel<<<nb4, 256, 0, stream>>>(row_start, sorted_src, g, es2, ed2,
                                         b2, out, N);
}